// Round 1
// baseline (3790.678 us; speedup 1.0000x reference)
//
#include <hip/hip_runtime.h>
#include <math.h>

// AttentionBlock: B=8, C=256, HW=4096, GroupNorm(8) -> QKV -> attn -> proj -> +x
// Round 0: correct fp32 baseline.
//   K1 gn_stats:  per-(b,group) mean/var -> per-(b,c) affine s,t      (tiny)
//   K2 qkv_gemm:  qkv[b,o,n] = sum_c qkv_w[o,c]*(x*s+t) + qkv_b      (12.9 GF)
//   K3 attn:      flash-style online softmax, 64-query tiles          (137 GF)
//   K4 out_gemm:  y = out_w @ attn_out + out_b + x                    (4.3 GF)
// ws: s,t (16KB) | qkv fp32 (96MB) | tmp fp32 (32MB)

#define Bn 8
#define Cn 256
#define HWn 4096
#define Gn 8
#define CPGn 32
#define Mqkv 768
#define EPSf 1e-5f
#define SCALEf 0.0625f   // 1/sqrt(256)

// ---------------- K1: group-norm stats -> per-channel affine ----------------
__global__ __launch_bounds__(1024)
void gn_stats_kernel(const float* __restrict__ x, const float* __restrict__ gn_w,
                     const float* __restrict__ gn_b, float* __restrict__ s_out,
                     float* __restrict__ t_out) {
  const int b = blockIdx.x / Gn, g = blockIdx.x % Gn;
  const float4* base = (const float4*)(x + ((size_t)(b * Cn + g * CPGn)) * HWn);
  const int n4 = CPGn * HWn / 4;  // 32768 float4s
  float sum = 0.f, sq = 0.f;
  for (int i = threadIdx.x; i < n4; i += 1024) {
    float4 v = base[i];
    sum += (v.x + v.y) + (v.z + v.w);
    sq  += (v.x * v.x + v.y * v.y) + (v.z * v.z + v.w * v.w);
  }
  __shared__ float ss[1024], s2[1024];
  ss[threadIdx.x] = sum; s2[threadIdx.x] = sq;
  __syncthreads();
  for (int off = 512; off > 0; off >>= 1) {
    if ((int)threadIdx.x < off) {
      ss[threadIdx.x] += ss[threadIdx.x + off];
      s2[threadIdx.x] += s2[threadIdx.x + off];
    }
    __syncthreads();
  }
  if (threadIdx.x < CPGn) {
    const float inv_n = 1.f / (float)(CPGn * HWn);
    float mean = ss[0] * inv_n;
    float var  = s2[0] * inv_n - mean * mean;
    float rstd = rsqrtf(var + EPSf);
    int c = g * CPGn + (int)threadIdx.x;
    float sc = gn_w[c] * rstd;
    s_out[b * Cn + c] = sc;
    t_out[b * Cn + c] = gn_b[c] - mean * sc;
  }
}

// ---------------- K2: QKV GEMM (fused GN affine) ----------------
// qkv[b][o][n] = sum_c w[o][c] * (x[b][c][n]*s[b,c] + t[b,c]) + wb[o]
// 64x64 tile, K-step 16, 256 threads (16x16), 4x4 regs/thread.
__global__ __launch_bounds__(256)
void qkv_gemm_kernel(const float* __restrict__ x, const float* __restrict__ w,
                     const float* __restrict__ wb, const float* __restrict__ s_aff,
                     const float* __restrict__ t_aff, float* __restrict__ out) {
  const int b = blockIdx.z;
  const int m0 = blockIdx.y * 64, n0 = blockIdx.x * 64;
  const int tid = threadIdx.x, tx = tid & 15, ty = tid >> 4;
  __shared__ float As[16][68];  // [k][m], padded
  __shared__ float Bs[16][68];  // [k][n], padded
  const float* xb = x + (size_t)b * Cn * HWn;
  const float* sb = s_aff + b * Cn;
  const float* tb = t_aff + b * Cn;
  float acc[4][4] = {};
  const int am = tid >> 2, ak = (tid & 3) * 4;   // A staging: 64m x 16k
  const int bk = tid >> 4, bn = (tid & 15) * 4;  // B staging: 16k x 64n
  for (int k0 = 0; k0 < Cn; k0 += 16) {
    {
      float4 a = *(const float4*)(w + (size_t)(m0 + am) * Cn + (k0 + ak));
      As[ak + 0][am] = a.x; As[ak + 1][am] = a.y; As[ak + 2][am] = a.z; As[ak + 3][am] = a.w;
      int c = k0 + bk;
      float4 v = *(const float4*)(xb + (size_t)c * HWn + (n0 + bn));
      float sc = sb[c], sh = tb[c];
      Bs[bk][bn + 0] = v.x * sc + sh; Bs[bk][bn + 1] = v.y * sc + sh;
      Bs[bk][bn + 2] = v.z * sc + sh; Bs[bk][bn + 3] = v.w * sc + sh;
    }
    __syncthreads();
#pragma unroll
    for (int kk = 0; kk < 16; ++kk) {
      float4 av = *(const float4*)&As[kk][ty * 4];
      float4 bv = *(const float4*)&Bs[kk][tx * 4];
      float aa[4] = {av.x, av.y, av.z, av.w};
      float bb[4] = {bv.x, bv.y, bv.z, bv.w};
#pragma unroll
      for (int i2 = 0; i2 < 4; ++i2)
#pragma unroll
        for (int j2 = 0; j2 < 4; ++j2)
          acc[i2][j2] = fmaf(aa[i2], bb[j2], acc[i2][j2]);
    }
    __syncthreads();
  }
  float* ob = out + (size_t)b * Mqkv * HWn;
#pragma unroll
  for (int i2 = 0; i2 < 4; ++i2) {
    int m = m0 + ty * 4 + i2;
    float bias = wb[m];
    float4 r;
    r.x = acc[i2][0] + bias; r.y = acc[i2][1] + bias;
    r.z = acc[i2][2] + bias; r.w = acc[i2][3] + bias;
    *(float4*)(ob + (size_t)m * HWn + n0 + tx * 4) = r;
  }
}

// ---------------- K3: flash attention fp32 ----------------
// Block = (b, 64-query tile). j-tiles of 64, online softmax.
// Thread (tx,ty): S rows i=ty*4+u, cols j=tx*4+v; O rows same i, cols c=cc*16+tx.
__global__ __launch_bounds__(256)
void attn_kernel(const float* __restrict__ qkv, float* __restrict__ outp) {
  const int b = blockIdx.y;
  const int i0 = blockIdx.x * 64;
  const int tid = threadIdx.x, tx = tid & 15, ty = tid >> 4;
  const float* q = qkv + (size_t)b * Mqkv * HWn;
  const float* k = q + (size_t)Cn * HWn;
  const float* v = k + (size_t)Cn * HWn;
  __shared__ float qs[16][68];
  __shared__ float ks[16][68];
  __shared__ float ps[64][68];
  __shared__ float vsT[16][260];

  float m_i[4], l_i[4];
  float o_acc[4][16];
#pragma unroll
  for (int u = 0; u < 4; ++u) {
    m_i[u] = -INFINITY; l_i[u] = 0.f;
#pragma unroll
    for (int cc = 0; cc < 16; ++cc) o_acc[u][cc] = 0.f;
  }
  const int sk = tid >> 4, scol = (tid & 15) * 4;  // qs/ks staging
  const int vjj = (tid & 3) * 4, vcb = tid >> 2;   // vsT staging

  for (int j0 = 0; j0 < HWn; j0 += 64) {
    // ---- S = (q^T k) tile, K-dim = 256 channels in chunks of 16 ----
    float s_acc[4][4] = {};
    for (int c0 = 0; c0 < Cn; c0 += 16) {
      *(float4*)&qs[sk][scol] = *(const float4*)(q + (size_t)(c0 + sk) * HWn + i0 + scol);
      *(float4*)&ks[sk][scol] = *(const float4*)(k + (size_t)(c0 + sk) * HWn + j0 + scol);
      __syncthreads();
#pragma unroll
      for (int kk = 0; kk < 16; ++kk) {
        float4 av = *(const float4*)&qs[kk][ty * 4];
        float4 bv = *(const float4*)&ks[kk][tx * 4];
        float aa[4] = {av.x, av.y, av.z, av.w};
        float bb[4] = {bv.x, bv.y, bv.z, bv.w};
#pragma unroll
        for (int i2 = 0; i2 < 4; ++i2)
#pragma unroll
          for (int j2 = 0; j2 < 4; ++j2)
            s_acc[i2][j2] = fmaf(aa[i2], bb[j2], s_acc[i2][j2]);
      }
      __syncthreads();
    }
    // ---- online softmax (all 64 lanes active; tx-group allreduce via shfl) ----
#pragma unroll
    for (int u = 0; u < 4; ++u) {
      float s0 = s_acc[u][0] * SCALEf, s1 = s_acc[u][1] * SCALEf;
      float s2 = s_acc[u][2] * SCALEf, s3 = s_acc[u][3] * SCALEf;
      float rm = fmaxf(fmaxf(s0, s1), fmaxf(s2, s3));
#pragma unroll
      for (int d = 1; d < 16; d <<= 1) rm = fmaxf(rm, __shfl_xor(rm, d, 64));
      float mn = fmaxf(m_i[u], rm);
      float alpha = expf(m_i[u] - mn);  // first tile: exp(-inf)=0
      float p0 = expf(s0 - mn), p1 = expf(s1 - mn);
      float p2 = expf(s2 - mn), p3 = expf(s3 - mn);
      float rs = (p0 + p1) + (p2 + p3);
#pragma unroll
      for (int d = 1; d < 16; d <<= 1) rs += __shfl_xor(rs, d, 64);
      l_i[u] = l_i[u] * alpha + rs;
      m_i[u] = mn;
#pragma unroll
      for (int cc = 0; cc < 16; ++cc) o_acc[u][cc] *= alpha;
      int ir = ty * 4 + u;
      ps[ir][tx * 4 + 0] = p0; ps[ir][tx * 4 + 1] = p1;
      ps[ir][tx * 4 + 2] = p2; ps[ir][tx * 4 + 3] = p3;
    }
    // ---- O += P * V^T over this j-tile, in 16-j sub-chunks ----
#pragma unroll 1
    for (int jj0 = 0; jj0 < 64; jj0 += 16) {
#pragma unroll
      for (int qq = 0; qq < 4; ++qq) {
        int c = vcb + 64 * qq;
        float4 vv = *(const float4*)(v + (size_t)c * HWn + j0 + jj0 + vjj);
        vsT[vjj + 0][c] = vv.x; vsT[vjj + 1][c] = vv.y;
        vsT[vjj + 2][c] = vv.z; vsT[vjj + 3][c] = vv.w;
      }
      __syncthreads();  // makes ps (first sub-chunk) and vsT visible
#pragma unroll
      for (int jj = 0; jj < 16; ++jj) {
        float pv0 = ps[ty * 4 + 0][jj0 + jj];
        float pv1 = ps[ty * 4 + 1][jj0 + jj];
        float pv2 = ps[ty * 4 + 2][jj0 + jj];
        float pv3 = ps[ty * 4 + 3][jj0 + jj];
#pragma unroll
        for (int cc = 0; cc < 16; ++cc) {
          float vvv = vsT[jj][cc * 16 + tx];
          o_acc[0][cc] = fmaf(pv0, vvv, o_acc[0][cc]);
          o_acc[1][cc] = fmaf(pv1, vvv, o_acc[1][cc]);
          o_acc[2][cc] = fmaf(pv2, vvv, o_acc[2][cc]);
          o_acc[3][cc] = fmaf(pv3, vvv, o_acc[3][cc]);
        }
      }
      __syncthreads();
    }
  }
  // ---- epilogue: divide by softmax denom, write [c][i] layout ----
  float* ob = outp + (size_t)b * Cn * HWn;
#pragma unroll
  for (int u = 0; u < 4; ++u) {
    float inv = 1.f / l_i[u];
    int i = i0 + ty * 4 + u;
#pragma unroll
    for (int cc = 0; cc < 16; ++cc) {
      ob[(size_t)(cc * 16 + tx) * HWn + i] = o_acc[u][cc] * inv;
    }
  }
}

// ---------------- K4: output projection + bias + residual ----------------
__global__ __launch_bounds__(256)
void out_gemm_kernel(const float* __restrict__ tmp, const float* __restrict__ w,
                     const float* __restrict__ wb, const float* __restrict__ xres,
                     float* __restrict__ y) {
  const int b = blockIdx.z;
  const int m0 = blockIdx.y * 64, n0 = blockIdx.x * 64;
  const int tid = threadIdx.x, tx = tid & 15, ty = tid >> 4;
  __shared__ float As[16][68];
  __shared__ float Bs[16][68];
  const float* tb = tmp + (size_t)b * Cn * HWn;
  float acc[4][4] = {};
  const int am = tid >> 2, ak = (tid & 3) * 4;
  const int bk = tid >> 4, bn = (tid & 15) * 4;
  for (int k0 = 0; k0 < Cn; k0 += 16) {
    {
      float4 a = *(const float4*)(w + (size_t)(m0 + am) * Cn + (k0 + ak));
      As[ak + 0][am] = a.x; As[ak + 1][am] = a.y; As[ak + 2][am] = a.z; As[ak + 3][am] = a.w;
      int c = k0 + bk;
      float4 vv = *(const float4*)(tb + (size_t)c * HWn + (n0 + bn));
      Bs[bk][bn + 0] = vv.x; Bs[bk][bn + 1] = vv.y; Bs[bk][bn + 2] = vv.z; Bs[bk][bn + 3] = vv.w;
    }
    __syncthreads();
#pragma unroll
    for (int kk = 0; kk < 16; ++kk) {
      float4 av = *(const float4*)&As[kk][ty * 4];
      float4 bv = *(const float4*)&Bs[kk][tx * 4];
      float aa[4] = {av.x, av.y, av.z, av.w};
      float bb[4] = {bv.x, bv.y, bv.z, bv.w};
#pragma unroll
      for (int i2 = 0; i2 < 4; ++i2)
#pragma unroll
        for (int j2 = 0; j2 < 4; ++j2)
          acc[i2][j2] = fmaf(aa[i2], bb[j2], acc[i2][j2]);
    }
    __syncthreads();
  }
  float* yb = y + (size_t)b * Cn * HWn;
  const float* xb = xres + (size_t)b * Cn * HWn;
#pragma unroll
  for (int i2 = 0; i2 < 4; ++i2) {
    int m = m0 + ty * 4 + i2;
    float bias = wb[m];
    float4 xr = *(const float4*)(xb + (size_t)m * HWn + n0 + tx * 4);
    float4 r;
    r.x = acc[i2][0] + bias + xr.x; r.y = acc[i2][1] + bias + xr.y;
    r.z = acc[i2][2] + bias + xr.z; r.w = acc[i2][3] + bias + xr.w;
    *(float4*)(yb + (size_t)m * HWn + n0 + tx * 4) = r;
  }
}

extern "C" void kernel_launch(void* const* d_in, const int* in_sizes, int n_in,
                              void* d_out, int out_size, void* d_ws, size_t ws_size,
                              hipStream_t stream) {
  (void)in_sizes; (void)n_in; (void)out_size; (void)ws_size;
  const float* x     = (const float*)d_in[0];
  const float* gn_w  = (const float*)d_in[1];
  const float* gn_b  = (const float*)d_in[2];
  const float* qkv_w = (const float*)d_in[3];
  const float* qkv_b = (const float*)d_in[4];
  const float* out_w = (const float*)d_in[5];
  const float* out_b = (const float*)d_in[6];
  float* out = (float*)d_out;

  char* ws = (char*)d_ws;
  float* s_aff = (float*)ws;                       // B*C
  float* t_aff = s_aff + Bn * Cn;                  // B*C
  float* qkv   = (float*)(ws + 16384);             // B*768*4096 fp32 = 96MB
  float* tmp   = qkv + (size_t)Bn * Mqkv * HWn;    // B*256*4096 fp32 = 32MB

  gn_stats_kernel<<<dim3(Bn * Gn), 1024, 0, stream>>>(x, gn_w, gn_b, s_aff, t_aff);
  qkv_gemm_kernel<<<dim3(64, 12, Bn), 256, 0, stream>>>(x, qkv_w, qkv_b, s_aff, t_aff, qkv);
  attn_kernel<<<dim3(64, Bn), 256, 0, stream>>>(qkv, tmp);
  out_gemm_kernel<<<dim3(64, 4, Bn), 256, 0, stream>>>(tmp, out_w, out_b, x, out);
}

// Round 3
// 734.282 us; speedup vs baseline: 5.1624x; 5.1624x over previous
//
#include <hip/hip_runtime.h>
#include <math.h>

// AttentionBlock: B=8, C=256, HW=4096. Round 3: bf16-MFMA flash attention (V-staging fix).
//   K1 gn_stats:  per-(b,group) mean/var -> per-(b,c) affine s,t
//   K2 qkv_gemm:  fp32 GEMM (GN fused); epilogue emits Qt/Kt [n][c] bf16, V [c][n] bf16
//   K3 attn:      flash attention, mfma_f32_16x16x32_bf16, fp32 softmax/accum
//   K4 out_gemm:  fp32 GEMM + bias + residual
// ws: s,t (16KB) | Qt 16MB | Kt 16MB | V 16MB | tmp fp32 32MB

#define Bn 8
#define Cn 256
#define HWn 4096
#define Gn 8
#define CPGn 32
#define Mqkv 768
#define EPSf 1e-5f
#define SCALEf 0.0625f   // 1/sqrt(256)

typedef short bf16x8 __attribute__((ext_vector_type(8)));
typedef float f32x4 __attribute__((ext_vector_type(4)));

__device__ __forceinline__ unsigned short f2bf(float f) {
  union { float f; unsigned u; } v; v.f = f;
  unsigned r = v.u + 0x7FFFu + ((v.u >> 16) & 1u);  // RNE
  return (unsigned short)(r >> 16);
}

// ---------------- K1: group-norm stats -> per-channel affine ----------------
__global__ __launch_bounds__(1024)
void gn_stats_kernel(const float* __restrict__ x, const float* __restrict__ gn_w,
                     const float* __restrict__ gn_b, float* __restrict__ s_out,
                     float* __restrict__ t_out) {
  const int b = blockIdx.x / Gn, g = blockIdx.x % Gn;
  const float4* base = (const float4*)(x + ((size_t)(b * Cn + g * CPGn)) * HWn);
  const int n4 = CPGn * HWn / 4;
  float sum = 0.f, sq = 0.f;
  for (int i = threadIdx.x; i < n4; i += 1024) {
    float4 v = base[i];
    sum += (v.x + v.y) + (v.z + v.w);
    sq  += (v.x * v.x + v.y * v.y) + (v.z * v.z + v.w * v.w);
  }
  __shared__ float ss[1024], s2[1024];
  ss[threadIdx.x] = sum; s2[threadIdx.x] = sq;
  __syncthreads();
  for (int off = 512; off > 0; off >>= 1) {
    if ((int)threadIdx.x < off) {
      ss[threadIdx.x] += ss[threadIdx.x + off];
      s2[threadIdx.x] += s2[threadIdx.x + off];
    }
    __syncthreads();
  }
  if (threadIdx.x < CPGn) {
    const float inv_n = 1.f / (float)(CPGn * HWn);
    float mean = ss[0] * inv_n;
    float var  = s2[0] * inv_n - mean * mean;
    float rstd = rsqrtf(var + EPSf);
    int c = g * CPGn + (int)threadIdx.x;
    float sc = gn_w[c] * rstd;
    s_out[b * Cn + c] = sc;
    t_out[b * Cn + c] = gn_b[c] - mean * sc;
  }
}

// ---------------- K2: QKV GEMM (fp32) -> bf16 Q^T/K^T/V ----------------
// qkv[o][n] = sum_c w[o][c]*(x[c][n]*s+t) + wb[o]
// Q (o<256):   Qt[b][n][o]      bf16   (transposed for MFMA A-operand)
// K (256..511):Kt[b][n][o-256]  bf16
// V (512..767):Vb[b][o-512][n]  bf16
__global__ __launch_bounds__(256)
void qkv_gemm_kernel(const float* __restrict__ x, const float* __restrict__ w,
                     const float* __restrict__ wb, const float* __restrict__ s_aff,
                     const float* __restrict__ t_aff, unsigned short* __restrict__ Qt,
                     unsigned short* __restrict__ Kt, unsigned short* __restrict__ Vb) {
  const int b = blockIdx.z;
  const int m0 = blockIdx.y * 64, n0 = blockIdx.x * 64;
  const int tid = threadIdx.x, tx = tid & 15, ty = tid >> 4;
  __shared__ float As[16][68];
  __shared__ float Bs[16][68];
  const float* xb = x + (size_t)b * Cn * HWn;
  const float* sb = s_aff + b * Cn;
  const float* tb = t_aff + b * Cn;
  float acc[4][4] = {};
  const int am = tid >> 2, ak = (tid & 3) * 4;
  const int bk = tid >> 4, bn = (tid & 15) * 4;
  for (int k0 = 0; k0 < Cn; k0 += 16) {
    {
      float4 a = *(const float4*)(w + (size_t)(m0 + am) * Cn + (k0 + ak));
      As[ak + 0][am] = a.x; As[ak + 1][am] = a.y; As[ak + 2][am] = a.z; As[ak + 3][am] = a.w;
      int c = k0 + bk;
      float4 v = *(const float4*)(xb + (size_t)c * HWn + (n0 + bn));
      float sc = sb[c], sh = tb[c];
      Bs[bk][bn + 0] = v.x * sc + sh; Bs[bk][bn + 1] = v.y * sc + sh;
      Bs[bk][bn + 2] = v.z * sc + sh; Bs[bk][bn + 3] = v.w * sc + sh;
    }
    __syncthreads();
#pragma unroll
    for (int kk = 0; kk < 16; ++kk) {
      float4 av = *(const float4*)&As[kk][ty * 4];
      float4 bv = *(const float4*)&Bs[kk][tx * 4];
      float aa[4] = {av.x, av.y, av.z, av.w};
      float bb[4] = {bv.x, bv.y, bv.z, bv.w};
#pragma unroll
      for (int i2 = 0; i2 < 4; ++i2)
#pragma unroll
        for (int j2 = 0; j2 < 4; ++j2)
          acc[i2][j2] = fmaf(aa[i2], bb[j2], acc[i2][j2]);
    }
    __syncthreads();
  }
  float bias[4];
#pragma unroll
  for (int i2 = 0; i2 < 4; ++i2) bias[i2] = wb[m0 + ty * 4 + i2];

  if (m0 < 512) {  // Q or K -> transposed [n][c] bf16
    unsigned short* dst = (m0 < 256) ? Qt : Kt;
    const int cbase = (m0 & 255) + ty * 4;
#pragma unroll
    for (int j2 = 0; j2 < 4; ++j2) {
      int n = n0 + tx * 4 + j2;
      ushort4 pk;
      pk.x = f2bf(acc[0][j2] + bias[0]);
      pk.y = f2bf(acc[1][j2] + bias[1]);
      pk.z = f2bf(acc[2][j2] + bias[2]);
      pk.w = f2bf(acc[3][j2] + bias[3]);
      *(ushort4*)(dst + ((size_t)(b * HWn + n) * Cn + cbase)) = pk;
    }
  } else {  // V -> [c][n] bf16
#pragma unroll
    for (int i2 = 0; i2 < 4; ++i2) {
      int c = (m0 - 512) + ty * 4 + i2;
      ushort4 pk;
      pk.x = f2bf(acc[i2][0] + bias[i2]);
      pk.y = f2bf(acc[i2][1] + bias[i2]);
      pk.z = f2bf(acc[i2][2] + bias[i2]);
      pk.w = f2bf(acc[i2][3] + bias[i2]);
      *(ushort4*)(Vb + ((size_t)(b * Cn + c) * HWn + n0 + tx * 4)) = pk;
    }
  }
}

// ---------------- K3: flash attention, bf16 MFMA ----------------
// Block = (b, 64-query tile), 4 waves; wave w owns rows i0+w*16..+16.
// Q frags hoisted to regs. K/V tiles in LDS (XOR-swizzled). P via per-wave LDS.
__global__ __launch_bounds__(256, 2)
void attn_kernel(const unsigned short* __restrict__ Qt,
                 const unsigned short* __restrict__ Kt,
                 const unsigned short* __restrict__ Vb,
                 float* __restrict__ outp) {
  const int b = blockIdx.y, i0 = blockIdx.x * 64;
  const int tid = threadIdx.x;
  const int wv = tid >> 6, l = tid & 63;
  const int l15 = l & 15, lq = l >> 4;

  __shared__ unsigned short Ks[64 * 256];       // [j][c], rows 512B, ^((j&7)<<4)
  __shared__ unsigned short Vs[256 * 64];       // [c][j], rows 128B, ^((c&7)<<4)
  __shared__ unsigned short Pa[4 * 16 * 64];    // per-wave [i][j], rows 128B, ^((i&7)<<4)
  unsigned short* Ps = Pa + wv * (16 * 64);

  const unsigned short* Qb = Qt + ((size_t)b * HWn + i0) * Cn;
  const unsigned short* Kb = Kt + (size_t)b * HWn * Cn;
  const unsigned short* Vg = Vb + (size_t)b * Cn * HWn;

  // hoist Q fragments: A[i=l15][k = kc*32 + lq*8 + t]
  bf16x8 qf[8];
  {
    const unsigned short* qrow = Qb + (size_t)(wv * 16 + l15) * Cn + lq * 8;
#pragma unroll
    for (int kc = 0; kc < 8; ++kc)
      qf[kc] = *(const bf16x8*)(qrow + kc * 32);
  }

  f32x4 o_acc[16];
#pragma unroll
  for (int cs = 0; cs < 16; ++cs) o_acc[cs] = (f32x4)(0.f);
  float m_i[4] = {-INFINITY, -INFINITY, -INFINITY, -INFINITY};
  float l_i[4] = {0.f, 0.f, 0.f, 0.f};

#pragma unroll 1
  for (int j0 = 0; j0 < HWn; j0 += 64) {
    // ---- stage K tile: 64 rows x 512B (8x256x16B = 32KB) ----
#pragma unroll
    for (int q = 0; q < 8; ++q) {
      int m = tid + 256 * q;
      int row = m >> 5, col = m & 31;
      bf16x8 kv = *(const bf16x8*)(Kb + (size_t)(j0 + row) * Cn + col * 8);
      int bofs = (row * 512 + col * 16) ^ ((row & 7) << 4);
      *(bf16x8*)((char*)Ks + bofs) = kv;
    }
    // ---- stage V tile: 256 rows x 128B (8x256x16B = 32KB) ----
#pragma unroll
    for (int q = 0; q < 8; ++q) {
      int m = tid + 256 * q;
      int c = m >> 3, col = m & 7;
      bf16x8 vv = *(const bf16x8*)(Vg + (size_t)c * HWn + j0 + col * 8);
      int bofs = (c * 128 + col * 16) ^ ((c & 7) << 4);
      *(bf16x8*)((char*)Vs + bofs) = vv;
    }
    __syncthreads();

    // ---- S = Q K^T (4 j-subtiles x 8 k-chunks) ----
    f32x4 s_acc[4];
#pragma unroll
    for (int s = 0; s < 4; ++s) s_acc[s] = (f32x4)(0.f);
#pragma unroll
    for (int s = 0; s < 4; ++s) {
      int j = s * 16 + l15;
#pragma unroll
      for (int kc = 0; kc < 8; ++kc) {
        int bofs = (j * 512 + kc * 64 + lq * 16) ^ ((j & 7) << 4);
        bf16x8 kf = *(const bf16x8*)((char*)Ks + bofs);
        s_acc[s] = __builtin_amdgcn_mfma_f32_16x16x32_bf16(qf[kc], kf, s_acc[s], 0, 0, 0);
      }
    }

    // ---- online softmax: lane owns rows (lq*4+r), cols s*16+l15 ----
    float pr[4][4];  // [s][r]
    float alpha[4];
#pragma unroll
    for (int r = 0; r < 4; ++r) {
      float v0 = s_acc[0][r] * SCALEf, v1 = s_acc[1][r] * SCALEf;
      float v2 = s_acc[2][r] * SCALEf, v3 = s_acc[3][r] * SCALEf;
      float rm = fmaxf(fmaxf(v0, v1), fmaxf(v2, v3));
#pragma unroll
      for (int d = 1; d < 16; d <<= 1) rm = fmaxf(rm, __shfl_xor(rm, d));
      float mn = fmaxf(m_i[r], rm);
      alpha[r] = __expf(m_i[r] - mn);
      m_i[r] = mn;
      float p0 = __expf(v0 - mn), p1 = __expf(v1 - mn);
      float p2 = __expf(v2 - mn), p3 = __expf(v3 - mn);
      float rs = (p0 + p1) + (p2 + p3);
#pragma unroll
      for (int d = 1; d < 16; d <<= 1) rs += __shfl_xor(rs, d);
      l_i[r] = l_i[r] * alpha[r] + rs;
      pr[0][r] = p0; pr[1][r] = p1; pr[2][r] = p2; pr[3][r] = p3;
    }
    // write P (bf16) to per-wave LDS, transposing frag layout -> A layout
#pragma unroll
    for (int r = 0; r < 4; ++r) {
      int row = lq * 4 + r;
#pragma unroll
      for (int s = 0; s < 4; ++s) {
        int bofs = (row * 128 + (s * 16 + l15) * 2) ^ ((row & 7) << 4);
        *(unsigned short*)((char*)Ps + bofs) = f2bf(pr[s][r]);
      }
    }
    // rescale O
#pragma unroll
    for (int cs = 0; cs < 16; ++cs) {
#pragma unroll
      for (int r = 0; r < 4; ++r) o_acc[cs][r] *= alpha[r];
    }
    // read P as A-frags (same-wave LDS; compiler inserts lgkmcnt)
    bf16x8 pa[2];
#pragma unroll
    for (int jc = 0; jc < 2; ++jc) {
      int bofs = (l15 * 128 + jc * 64 + lq * 16) ^ ((l15 & 7) << 4);
      pa[jc] = *(const bf16x8*)((char*)Ps + bofs);
    }
    // ---- O += P V : 16 c-subtiles x 2 j-chunks ----
#pragma unroll
    for (int cs = 0; cs < 16; ++cs) {
      int c = cs * 16 + l15;
#pragma unroll
      for (int jc = 0; jc < 2; ++jc) {
        int bofs = (c * 128 + jc * 64 + lq * 16) ^ ((c & 7) << 4);
        bf16x8 vf = *(const bf16x8*)((char*)Vs + bofs);
        o_acc[cs] = __builtin_amdgcn_mfma_f32_16x16x32_bf16(pa[jc], vf, o_acc[cs], 0, 0, 0);
      }
    }
    __syncthreads();
  }

  // ---- epilogue: O /= l, write tmp fp32 [c][i] ----
  float inv[4];
#pragma unroll
  for (int r = 0; r < 4; ++r) inv[r] = 1.f / l_i[r];
  float* ob = outp + (size_t)b * Cn * HWn;
  const int ibase = i0 + wv * 16 + lq * 4;
#pragma unroll
  for (int cs = 0; cs < 16; ++cs) {
    int c = cs * 16 + l15;
    float4 r4;
    r4.x = o_acc[cs][0] * inv[0];
    r4.y = o_acc[cs][1] * inv[1];
    r4.z = o_acc[cs][2] * inv[2];
    r4.w = o_acc[cs][3] * inv[3];
    *(float4*)(ob + (size_t)c * HWn + ibase) = r4;
  }
}

// ---------------- K4: output projection + bias + residual ----------------
__global__ __launch_bounds__(256)
void out_gemm_kernel(const float* __restrict__ tmp, const float* __restrict__ w,
                     const float* __restrict__ wb, const float* __restrict__ xres,
                     float* __restrict__ y) {
  const int b = blockIdx.z;
  const int m0 = blockIdx.y * 64, n0 = blockIdx.x * 64;
  const int tid = threadIdx.x, tx = tid & 15, ty = tid >> 4;
  __shared__ float As[16][68];
  __shared__ float Bs[16][68];
  const float* tb = tmp + (size_t)b * Cn * HWn;
  float acc[4][4] = {};
  const int am = tid >> 2, ak = (tid & 3) * 4;
  const int bk = tid >> 4, bn = (tid & 15) * 4;
  for (int k0 = 0; k0 < Cn; k0 += 16) {
    {
      float4 a = *(const float4*)(w + (size_t)(m0 + am) * Cn + (k0 + ak));
      As[ak + 0][am] = a.x; As[ak + 1][am] = a.y; As[ak + 2][am] = a.z; As[ak + 3][am] = a.w;
      int c = k0 + bk;
      float4 vv = *(const float4*)(tb + (size_t)c * HWn + (n0 + bn));
      Bs[bk][bn + 0] = vv.x; Bs[bk][bn + 1] = vv.y; Bs[bk][bn + 2] = vv.z; Bs[bk][bn + 3] = vv.w;
    }
    __syncthreads();
#pragma unroll
    for (int kk = 0; kk < 16; ++kk) {
      float4 av = *(const float4*)&As[kk][ty * 4];
      float4 bv = *(const float4*)&Bs[kk][tx * 4];
      float aa[4] = {av.x, av.y, av.z, av.w};
      float bb[4] = {bv.x, bv.y, bv.z, bv.w};
#pragma unroll
      for (int i2 = 0; i2 < 4; ++i2)
#pragma unroll
        for (int j2 = 0; j2 < 4; ++j2)
          acc[i2][j2] = fmaf(aa[i2], bb[j2], acc[i2][j2]);
    }
    __syncthreads();
  }
  float* yb = y + (size_t)b * Cn * HWn;
  const float* xb = xres + (size_t)b * Cn * HWn;
#pragma unroll
  for (int i2 = 0; i2 < 4; ++i2) {
    int m = m0 + ty * 4 + i2;
    float bias = wb[m];
    float4 xr = *(const float4*)(xb + (size_t)m * HWn + n0 + tx * 4);
    float4 r;
    r.x = acc[i2][0] + bias + xr.x; r.y = acc[i2][1] + bias + xr.y;
    r.z = acc[i2][2] + bias + xr.z; r.w = acc[i2][3] + bias + xr.w;
    *(float4*)(yb + (size_t)m * HWn + n0 + tx * 4) = r;
  }
}

extern "C" void kernel_launch(void* const* d_in, const int* in_sizes, int n_in,
                              void* d_out, int out_size, void* d_ws, size_t ws_size,
                              hipStream_t stream) {
  (void)in_sizes; (void)n_in; (void)out_size; (void)ws_size;
  const float* x     = (const float*)d_in[0];
  const float* gn_w  = (const float*)d_in[1];
  const float* gn_b  = (const float*)d_in[2];
  const float* qkv_w = (const float*)d_in[3];
  const float* qkv_b = (const float*)d_in[4];
  const float* out_w = (const float*)d_in[5];
  const float* out_b = (const float*)d_in[6];
  float* out = (float*)d_out;

  char* ws = (char*)d_ws;
  float* s_aff = (float*)ws;                                   // B*C
  float* t_aff = s_aff + Bn * Cn;                              // B*C
  unsigned short* Qt = (unsigned short*)(ws + 16384);          // 16MB
  unsigned short* Kt = Qt + (size_t)Bn * HWn * Cn;             // 16MB
  unsigned short* Vb = Kt + (size_t)Bn * HWn * Cn;             // 16MB
  float* tmp = (float*)(Vb + (size_t)Bn * HWn * Cn);           // 32MB

  gn_stats_kernel<<<dim3(Bn * Gn), 1024, 0, stream>>>(x, gn_w, gn_b, s_aff, t_aff);
  qkv_gemm_kernel<<<dim3(64, 12, Bn), 256, 0, stream>>>(x, qkv_w, qkv_b, s_aff, t_aff, Qt, Kt, Vb);
  attn_kernel<<<dim3(64, Bn), 256, 0, stream>>>(Qt, Kt, Vb, tmp);
  out_gemm_kernel<<<dim3(64, 4, Bn), 256, 0, stream>>>(tmp, out_w, out_b, x, out);
}

// Round 5
// 497.583 us; speedup vs baseline: 7.6182x; 1.4757x over previous
//
#include <hip/hip_runtime.h>
#include <math.h>

// AttentionBlock: B=8, C=256, HW=4096. Round 5:
//   - swapped QK^T (mfma(K,Q)) -> per-lane softmax, P stays in registers
//   - chunk-linear LDS layout: all frag reads/writes = lane*16 + imm (0 addr VALU,
//     conflict-free both sides); permutation folded into global staging addresses
//   - P->bf16 via v_cvt_pk_bf16_f32; redistribute via 16 shuffles + post-select
//   - register double-buffer staging (T14): next tile loads overlap compute
// ws: s,t (16KB) | Qt 16MB | Kt 16MB | V 16MB | tmp fp32 32MB

#define Bn 8
#define Cn 256
#define HWn 4096
#define Gn 8
#define CPGn 32
#define Mqkv 768
#define EPSf 1e-5f
#define QSCALEf 0.0625f   // 1/sqrt(256), exact in bf16

typedef short bf16x8 __attribute__((ext_vector_type(8)));
typedef float f32x4 __attribute__((ext_vector_type(4)));

__device__ __forceinline__ unsigned short f2bf(float f) {
  union { float f; unsigned u; } v; v.f = f;
  unsigned r = v.u + 0x7FFFu + ((v.u >> 16) & 1u);  // RNE
  return (unsigned short)(r >> 16);
}

__device__ __forceinline__ int cvt_pk_bf16(float lo, float hi) {
  int d;
  asm("v_cvt_pk_bf16_f32 %0, %1, %2" : "=v"(d) : "v"(lo), "v"(hi));
  return d;
}

// ---------------- K1: group-norm stats -> per-channel affine ----------------
__global__ __launch_bounds__(1024)
void gn_stats_kernel(const float* __restrict__ x, const float* __restrict__ gn_w,
                     const float* __restrict__ gn_b, float* __restrict__ s_out,
                     float* __restrict__ t_out) {
  const int b = blockIdx.x / Gn, g = blockIdx.x % Gn;
  const float4* base = (const float4*)(x + ((size_t)(b * Cn + g * CPGn)) * HWn);
  const int n4 = CPGn * HWn / 4;
  float sum = 0.f, sq = 0.f;
  for (int i = threadIdx.x; i < n4; i += 1024) {
    float4 v = base[i];
    sum += (v.x + v.y) + (v.z + v.w);
    sq  += (v.x * v.x + v.y * v.y) + (v.z * v.z + v.w * v.w);
  }
  __shared__ float ss[1024], s2[1024];
  ss[threadIdx.x] = sum; s2[threadIdx.x] = sq;
  __syncthreads();
  for (int off = 512; off > 0; off >>= 1) {
    if ((int)threadIdx.x < off) {
      ss[threadIdx.x] += ss[threadIdx.x + off];
      s2[threadIdx.x] += s2[threadIdx.x + off];
    }
    __syncthreads();
  }
  if (threadIdx.x < CPGn) {
    const float inv_n = 1.f / (float)(CPGn * HWn);
    float mean = ss[0] * inv_n;
    float var  = s2[0] * inv_n - mean * mean;
    float rstd = rsqrtf(var + EPSf);
    int c = g * CPGn + (int)threadIdx.x;
    float sc = gn_w[c] * rstd;
    s_out[b * Cn + c] = sc;
    t_out[b * Cn + c] = gn_b[c] - mean * sc;
  }
}

// ---------------- K2: QKV GEMM (fp32) -> bf16 Q^T/K^T/V ----------------
__global__ __launch_bounds__(256)
void qkv_gemm_kernel(const float* __restrict__ x, const float* __restrict__ w,
                     const float* __restrict__ wb, const float* __restrict__ s_aff,
                     const float* __restrict__ t_aff, unsigned short* __restrict__ Qt,
                     unsigned short* __restrict__ Kt, unsigned short* __restrict__ Vb) {
  const int b = blockIdx.z;
  const int m0 = blockIdx.y * 64, n0 = blockIdx.x * 64;
  const int tid = threadIdx.x, tx = tid & 15, ty = tid >> 4;
  __shared__ float As[16][68];
  __shared__ float Bs[16][68];
  const float* xb = x + (size_t)b * Cn * HWn;
  const float* sb = s_aff + b * Cn;
  const float* tb = t_aff + b * Cn;
  float acc[4][4] = {};
  const int am = tid >> 2, ak = (tid & 3) * 4;
  const int bk = tid >> 4, bn = (tid & 15) * 4;
  for (int k0 = 0; k0 < Cn; k0 += 16) {
    {
      float4 a = *(const float4*)(w + (size_t)(m0 + am) * Cn + (k0 + ak));
      As[ak + 0][am] = a.x; As[ak + 1][am] = a.y; As[ak + 2][am] = a.z; As[ak + 3][am] = a.w;
      int c = k0 + bk;
      float4 v = *(const float4*)(xb + (size_t)c * HWn + (n0 + bn));
      float sc = sb[c], sh = tb[c];
      Bs[bk][bn + 0] = v.x * sc + sh; Bs[bk][bn + 1] = v.y * sc + sh;
      Bs[bk][bn + 2] = v.z * sc + sh; Bs[bk][bn + 3] = v.w * sc + sh;
    }
    __syncthreads();
#pragma unroll
    for (int kk = 0; kk < 16; ++kk) {
      float4 av = *(const float4*)&As[kk][ty * 4];
      float4 bv = *(const float4*)&Bs[kk][tx * 4];
      float aa[4] = {av.x, av.y, av.z, av.w};
      float bb[4] = {bv.x, bv.y, bv.z, bv.w};
#pragma unroll
      for (int i2 = 0; i2 < 4; ++i2)
#pragma unroll
        for (int j2 = 0; j2 < 4; ++j2)
          acc[i2][j2] = fmaf(aa[i2], bb[j2], acc[i2][j2]);
    }
    __syncthreads();
  }
  float bias[4];
#pragma unroll
  for (int i2 = 0; i2 < 4; ++i2) bias[i2] = wb[m0 + ty * 4 + i2];

  if (m0 < 512) {  // Q or K -> transposed [n][c] bf16; Q prescaled by 1/16
    unsigned short* dst = (m0 < 256) ? Qt : Kt;
    const float scl = (m0 < 256) ? QSCALEf : 1.0f;
    const int cbase = (m0 & 255) + ty * 4;
#pragma unroll
    for (int j2 = 0; j2 < 4; ++j2) {
      int n = n0 + tx * 4 + j2;
      ushort4 pk;
      pk.x = f2bf((acc[0][j2] + bias[0]) * scl);
      pk.y = f2bf((acc[1][j2] + bias[1]) * scl);
      pk.z = f2bf((acc[2][j2] + bias[2]) * scl);
      pk.w = f2bf((acc[3][j2] + bias[3]) * scl);
      *(ushort4*)(dst + ((size_t)(b * HWn + n) * Cn + cbase)) = pk;
    }
  } else {  // V -> [c][n] bf16
#pragma unroll
    for (int i2 = 0; i2 < 4; ++i2) {
      int c = (m0 - 512) + ty * 4 + i2;
      ushort4 pk;
      pk.x = f2bf(acc[i2][0] + bias[i2]);
      pk.y = f2bf(acc[i2][1] + bias[i2]);
      pk.z = f2bf(acc[i2][2] + bias[i2]);
      pk.w = f2bf(acc[i2][3] + bias[i2]);
      *(ushort4*)(Vb + ((size_t)(b * Cn + c) * HWn + n0 + tx * 4)) = pk;
    }
  }
}

// ---------------- K3: flash attention, bf16 MFMA, in-register softmax ----------------
// Block = (b, 64-query tile), 4 waves; wave wv owns Q rows i0+wv*16..+16.
// LDS chunk-linear layouts (16B chunks):
//   Ks chunk = kc*256 + s*64 + lane  holds K[j=s*16+(lane&15)][c=kc*32+(lane>>4)*8 ..+7]
//   Vs chunk = jc*1024 + cs*64 + lane holds V[c=cs*16+(lane&15)][j=jc*32+(lane>>4)*8 ..+7]
// => frag read addr = lane*16 + imm; staging write addr = tid*16 + q*4096. No conflicts.
__global__ __launch_bounds__(256, 2)
void attn_kernel(const unsigned short* __restrict__ Qt,
                 const unsigned short* __restrict__ Kt,
                 const unsigned short* __restrict__ Vb,
                 float* __restrict__ outp) {
  const int b = blockIdx.y, i0 = blockIdx.x * 64;
  const int tid = threadIdx.x;
  const int wv = tid >> 6, l = tid & 63;
  const int l15 = l & 15, lq = l >> 4;

  __shared__ unsigned short Ks[16384];  // 32KB
  __shared__ unsigned short Vs[16384];  // 32KB
  char* KsB = (char*)Ks;
  char* VsB = (char*)Vs;

  const unsigned short* Qb = Qt + ((size_t)b * HWn + i0) * Cn;
  const unsigned short* Kb = Kt + (size_t)b * HWn * Cn;
  const unsigned short* Vg = Vb + (size_t)b * Cn * HWn;

  // hoisted Q fragments (prescaled by 1/16): B-frag Q[i=l15][k=kc*32+lq*8+t]
  bf16x8 qf[8];
  {
    const unsigned short* qrow = Qb + (size_t)(wv * 16 + l15) * Cn + lq * 8;
#pragma unroll
    for (int kc = 0; kc < 8; ++kc) qf[kc] = *(const bf16x8*)(qrow + kc * 32);
  }

  // staging: thread tid owns LDS chunks q*256+tid (q=0..7)
  //   K: chunk -> row j = (tid>>6)*16+(tid&15), c-chunk m = q*4+((tid>>4)&3)
  //   V: chunk -> c = (q&3)*64 + (tid>>6)*16+(tid&15), j-chunk = (q>>2)*4+((tid>>4)&3)
  const int jt  = ((tid >> 6) << 4) | (tid & 15);
  const int lqt = (tid >> 4) & 3;
  const unsigned short* gK = Kb + (size_t)jt * Cn + lqt * 8;   // +q*32 elems
  const unsigned short* gV = Vg + (size_t)jt * HWn + lqt * 8;  // +(q&3)*64*HWn + (q>>2)*32

  // P redistribution lanes (post-shuffle select by shi = lq>>1)
  const int laneA = l15 + ((lq & 1) << 5);
  const int laneB = laneA + 16;
  const int shi = lq >> 1;

  bf16x8 kst[8], vst[8];
#pragma unroll
  for (int q = 0; q < 8; ++q) kst[q] = *(const bf16x8*)(gK + q * 32);
#pragma unroll
  for (int q = 0; q < 8; ++q)
    vst[q] = *(const bf16x8*)(gV + (size_t)(q & 3) * 64 * HWn + (q >> 2) * 32);
  gK += 64 * Cn; gV += 64;

  f32x4 o_acc[16];
#pragma unroll
  for (int cs = 0; cs < 16; ++cs) o_acc[cs] = (f32x4)(0.f);
  float m_i = -INFINITY, l_i = 0.f;

#pragma unroll 1
  for (int t = 0; t < 64; ++t) {
    // ---- write staged tile to LDS (compiler inserts vmcnt wait) ----
#pragma unroll
    for (int q = 0; q < 8; ++q) *(bf16x8*)(KsB + tid * 16 + q * 4096) = kst[q];
#pragma unroll
    for (int q = 0; q < 8; ++q) *(bf16x8*)(VsB + tid * 16 + q * 4096) = vst[q];
    __syncthreads();
    // ---- issue next-tile loads (overlap with compute) ----
    if (t < 63) {
#pragma unroll
      for (int q = 0; q < 8; ++q) kst[q] = *(const bf16x8*)(gK + q * 32);
#pragma unroll
      for (int q = 0; q < 8; ++q)
        vst[q] = *(const bf16x8*)(gV + (size_t)(q & 3) * 64 * HWn + (q >> 2) * 32);
      gK += 64 * Cn; gV += 64;
    }

    // ---- S^T = K Q^T: lane holds S[i=l15][j=16s+4lq+r] ----
    f32x4 s_acc[4];
#pragma unroll
    for (int s = 0; s < 4; ++s) s_acc[s] = (f32x4)(0.f);
#pragma unroll
    for (int kc = 0; kc < 8; ++kc) {
#pragma unroll
      for (int s = 0; s < 4; ++s) {
        bf16x8 kf = *(const bf16x8*)(KsB + l * 16 + s * 1024 + kc * 4096);
        s_acc[s] = __builtin_amdgcn_mfma_f32_16x16x32_bf16(kf, qf[kc], s_acc[s], 0, 0, 0);
      }
    }

    // ---- per-lane online softmax for row i=l15 (row spans lq via xor16/32) ----
    float p[4][4];
    float rm = -INFINITY;
#pragma unroll
    for (int s = 0; s < 4; ++s)
#pragma unroll
      for (int r = 0; r < 4; ++r) { p[s][r] = s_acc[s][r]; rm = fmaxf(rm, p[s][r]); }
    rm = fmaxf(rm, __shfl_xor(rm, 16));
    rm = fmaxf(rm, __shfl_xor(rm, 32));
    float mn = fmaxf(m_i, rm);
    float alpha = __expf(m_i - mn);
    m_i = mn;
    float rs = 0.f;
#pragma unroll
    for (int s = 0; s < 4; ++s)
#pragma unroll
      for (int r = 0; r < 4; ++r) { float e = __expf(p[s][r] - mn); p[s][r] = e; rs += e; }
    rs += __shfl_xor(rs, 16);
    rs += __shfl_xor(rs, 32);
    l_i = l_i * alpha + rs;

    // ---- pack P to bf16 dwords: d[s][u] = P[i][s*16+4*lq+2u .. +1] ----
    int d00 = cvt_pk_bf16(p[0][0], p[0][1]), d01 = cvt_pk_bf16(p[0][2], p[0][3]);
    int d10 = cvt_pk_bf16(p[1][0], p[1][1]), d11 = cvt_pk_bf16(p[1][2], p[1][3]);
    int d20 = cvt_pk_bf16(p[2][0], p[2][1]), d21 = cvt_pk_bf16(p[2][2], p[2][3]);
    int d30 = cvt_pk_bf16(p[3][0], p[3][1]), d31 = cvt_pk_bf16(p[3][2], p[3][3]);
    // ---- redistribute to PV A-frag pa[jc] = P[i=l15][j=32jc+8lq+t] ----
    // shuffle raw dwords; select AFTER the shuffle with consumer's shi.
    int A00 = __shfl(d00, laneA), A01 = __shfl(d01, laneA);
    int A10 = __shfl(d10, laneA), A11 = __shfl(d11, laneA);
    int B00 = __shfl(d00, laneB), B01 = __shfl(d01, laneB);
    int B10 = __shfl(d10, laneB), B11 = __shfl(d11, laneB);
    int A20 = __shfl(d20, laneA), A21 = __shfl(d21, laneA);
    int A30 = __shfl(d30, laneA), A31 = __shfl(d31, laneA);
    int B20 = __shfl(d20, laneB), B21 = __shfl(d21, laneB);
    int B30 = __shfl(d30, laneB), B31 = __shfl(d31, laneB);
    union { int w[4]; bf16x8 v; } pa0, pa1;
    pa0.w[0] = shi ? A10 : A00; pa0.w[1] = shi ? A11 : A01;
    pa0.w[2] = shi ? B10 : B00; pa0.w[3] = shi ? B11 : B01;
    pa1.w[0] = shi ? A30 : A20; pa1.w[1] = shi ? A31 : A21;
    pa1.w[2] = shi ? B30 : B20; pa1.w[3] = shi ? B31 : B21;

    // ---- rescale O: o_acc[cs][r] is row i=4lq+r; alpha lives at lane l15=i ----
    float a0 = __shfl(alpha, 4 * lq + 0);
    float a1 = __shfl(alpha, 4 * lq + 1);
    float a2 = __shfl(alpha, 4 * lq + 2);
    float a3 = __shfl(alpha, 4 * lq + 3);
#pragma unroll
    for (int cs = 0; cs < 16; ++cs) {
      o_acc[cs][0] *= a0; o_acc[cs][1] *= a1;
      o_acc[cs][2] *= a2; o_acc[cs][3] *= a3;
    }

    // ---- O += P V ----
#pragma unroll
    for (int cs = 0; cs < 16; ++cs) {
      bf16x8 vf0 = *(const bf16x8*)(VsB + l * 16 + cs * 1024);
      bf16x8 vf1 = *(const bf16x8*)(VsB + l * 16 + cs * 1024 + 16384);
      o_acc[cs] = __builtin_amdgcn_mfma_f32_16x16x32_bf16(pa0.v, vf0, o_acc[cs], 0, 0, 0);
      o_acc[cs] = __builtin_amdgcn_mfma_f32_16x16x32_bf16(pa1.v, vf1, o_acc[cs], 0, 0, 0);
    }
    __syncthreads();
  }

  // ---- epilogue: O /= l, write tmp fp32 [c][i] ----
  float il = 1.f / l_i;
  float i0v = __shfl(il, 4 * lq + 0);
  float i1v = __shfl(il, 4 * lq + 1);
  float i2v = __shfl(il, 4 * lq + 2);
  float i3v = __shfl(il, 4 * lq + 3);
  float* ob = outp + (size_t)b * Cn * HWn;
  const int ibase = i0 + wv * 16 + lq * 4;
#pragma unroll
  for (int cs = 0; cs < 16; ++cs) {
    int c = cs * 16 + l15;
    float4 r4;
    r4.x = o_acc[cs][0] * i0v;
    r4.y = o_acc[cs][1] * i1v;
    r4.z = o_acc[cs][2] * i2v;
    r4.w = o_acc[cs][3] * i3v;
    *(float4*)(ob + (size_t)c * HWn + ibase) = r4;
  }
}

// ---------------- K4: output projection + bias + residual ----------------
__global__ __launch_bounds__(256)
void out_gemm_kernel(const float* __restrict__ tmp, const float* __restrict__ w,
                     const float* __restrict__ wb, const float* __restrict__ xres,
                     float* __restrict__ y) {
  const int b = blockIdx.z;
  const int m0 = blockIdx.y * 64, n0 = blockIdx.x * 64;
  const int tid = threadIdx.x, tx = tid & 15, ty = tid >> 4;
  __shared__ float As[16][68];
  __shared__ float Bs[16][68];
  const float* tb = tmp + (size_t)b * Cn * HWn;
  float acc[4][4] = {};
  const int am = tid >> 2, ak = (tid & 3) * 4;
  const int bk = tid >> 4, bn = (tid & 15) * 4;
  for (int k0 = 0; k0 < Cn; k0 += 16) {
    {
      float4 a = *(const float4*)(w + (size_t)(m0 + am) * Cn + (k0 + ak));
      As[ak + 0][am] = a.x; As[ak + 1][am] = a.y; As[ak + 2][am] = a.z; As[ak + 3][am] = a.w;
      int c = k0 + bk;
      float4 vv = *(const float4*)(tb + (size_t)c * HWn + (n0 + bn));
      Bs[bk][bn + 0] = vv.x; Bs[bk][bn + 1] = vv.y; Bs[bk][bn + 2] = vv.z; Bs[bk][bn + 3] = vv.w;
    }
    __syncthreads();
#pragma unroll
    for (int kk = 0; kk < 16; ++kk) {
      float4 av = *(const float4*)&As[kk][ty * 4];
      float4 bv = *(const float4*)&Bs[kk][tx * 4];
      float aa[4] = {av.x, av.y, av.z, av.w};
      float bb[4] = {bv.x, bv.y, bv.z, bv.w};
#pragma unroll
      for (int i2 = 0; i2 < 4; ++i2)
#pragma unroll
        for (int j2 = 0; j2 < 4; ++j2)
          acc[i2][j2] = fmaf(aa[i2], bb[j2], acc[i2][j2]);
    }
    __syncthreads();
  }
  float* yb = y + (size_t)b * Cn * HWn;
  const float* xb = xres + (size_t)b * Cn * HWn;
#pragma unroll
  for (int i2 = 0; i2 < 4; ++i2) {
    int m = m0 + ty * 4 + i2;
    float bias = wb[m];
    float4 xr = *(const float4*)(xb + (size_t)m * HWn + n0 + tx * 4);
    float4 r;
    r.x = acc[i2][0] + bias + xr.x; r.y = acc[i2][1] + bias + xr.y;
    r.z = acc[i2][2] + bias + xr.z; r.w = acc[i2][3] + bias + xr.w;
    *(float4*)(yb + (size_t)m * HWn + n0 + tx * 4) = r;
  }
}

extern "C" void kernel_launch(void* const* d_in, const int* in_sizes, int n_in,
                              void* d_out, int out_size, void* d_ws, size_t ws_size,
                              hipStream_t stream) {
  (void)in_sizes; (void)n_in; (void)out_size; (void)ws_size;
  const float* x     = (const float*)d_in[0];
  const float* gn_w  = (const float*)d_in[1];
  const float* gn_b  = (const float*)d_in[2];
  const float* qkv_w = (const float*)d_in[3];
  const float* qkv_b = (const float*)d_in[4];
  const float* out_w = (const float*)d_in[5];
  const float* out_b = (const float*)d_in[6];
  float* out = (float*)d_out;

  char* ws = (char*)d_ws;
  float* s_aff = (float*)ws;                                   // B*C
  float* t_aff = s_aff + Bn * Cn;                              // B*C
  unsigned short* Qt = (unsigned short*)(ws + 16384);          // 16MB
  unsigned short* Kt = Qt + (size_t)Bn * HWn * Cn;             // 16MB
  unsigned short* Vb = Kt + (size_t)Bn * HWn * Cn;             // 16MB
  float* tmp = (float*)(Vb + (size_t)Bn * HWn * Cn);           // 32MB

  gn_stats_kernel<<<dim3(Bn * Gn), 1024, 0, stream>>>(x, gn_w, gn_b, s_aff, t_aff);
  qkv_gemm_kernel<<<dim3(64, 12, Bn), 256, 0, stream>>>(x, qkv_w, qkv_b, s_aff, t_aff, Qt, Kt, Vb);
  attn_kernel<<<dim3(64, Bn), 256, 0, stream>>>(Qt, Kt, Vb, tmp);
  out_gemm_kernel<<<dim3(64, 4, Bn), 256, 0, stream>>>(tmp, out_w, out_b, x, out);
}